// Round 3
// baseline (445.875 us; speedup 1.0000x reference)
//
#include <hip/hip_runtime.h>
#include <math.h>

#define TOPK 100
#define HW 65536                   // 256*256
#define SLICE_STRIDE (7*HW)        // 458752
#define NBATCH 32
#define NBOX 200
#define HM (3*HW)                  // 196608 heatmap elems per slice
#define CAP 4096                   // candidate cap (old per-slice path)
#define CCAP 2048                  // candidate cap (per-class path)
#define WS_NEED ((size_t)(192 * TOPK * 8))

// Order-preserving float->uint key: f1 > f2  <=>  key(f1) > key(f2)
__device__ __forceinline__ unsigned fkey(float f) {
    unsigned u = __float_as_uint(f);
    return (u & 0x80000000u) ? ~u : (u | 0x80000000u);
}

// Runtime-slot select over a 4-entry register array with constant indices only
__device__ __forceinline__ float sel4(const float a[4], int s) {
    float r = a[0];
    r = (s == 1) ? a[1] : r;
    r = (s == 2) ? a[2] : r;
    r = (s == 3) ? a[3] : r;
    return r;
}

// ===========================================================================
// NEW PATH
// ===========================================================================

// ---------------------------------------------------------------------------
// Kernel 1: exact top-100 per (slice, class) channel. 192 blocks x 1024 thr.
// Global top-100 of a slice is a subset of the union of per-class top-100s,
// and keys carry the GLOBAL index (c*HW + rem), so merging preserves the
// exact verified ordering (desc raw logit, ties -> lowest global index).
// Writes 100 sorted keys per block to ws[bid*100 ..].
// ---------------------------------------------------------------------------
__global__ __launch_bounds__(1024) void kcls(const float* __restrict__ x,
                                             unsigned long long* __restrict__ ws) {
    __shared__ unsigned hist[4096];                 // 16 KB
    __shared__ unsigned long long cand[CCAP];       // 16 KB (aliased as scan tmp)
    __shared__ int shB, shB2;
    __shared__ unsigned shAbove, shNcand, shNc;

    const int bid = blockIdx.x;
    const int slice = bid / 3, c = bid % 3;
    const int t = threadIdx.x;
    const float* xc = x + (size_t)slice * SLICE_STRIDE + (size_t)c * HW;
    const float4* xc4 = (const float4*)xc;
    const int N4 = HW / 4;                          // 16384

    if (t == 0) { shB = 0; shB2 = 0; shAbove = 0u; shNcand = 0u; shNc = 0u; }
    for (int i = t; i < 4096; i += 1024) hist[i] = 0u;
    __syncthreads();

    // ---- pass 1: histogram of top-12 key bits ----
    for (int i = t; i < N4; i += 1024) {
        float4 v = xc4[i];
        float a[4] = {v.x, v.y, v.z, v.w};
        #pragma unroll
        for (int c_ = 0; c_ < 4; ++c_) {
            unsigned vk = fkey(a[c_]);
            atomicAdd(&hist[vk >> 20], 1u);
        }
    }
    __syncthreads();

    // ---- parallel suffix-sum (Hillis-Steele ping-pong, 12 passes) ----
    {
        unsigned* tmp = (unsigned*)cand;            // 4096 words = 16 KB
        unsigned* src = hist;
        unsigned* dst = tmp;
        for (int d = 1; d < 4096; d <<= 1) {
            for (int i = t; i < 4096; i += 1024) {
                unsigned v = src[i];
                if (i + d < 4096) v += src[i + d];
                dst[i] = v;
            }
            __syncthreads();
            unsigned* sw = src; src = dst; dst = sw;
        }
        // boundary bin B: suffix[B] >= 100 > suffix[B+1] (unique; exists since
        // suffix[0] = HW >= 100 and suffix past the end is 0)
        for (int i = t; i < 4096; i += 1024) {
            unsigned sb = src[i];
            unsigned sn = (i < 4095) ? src[i + 1] : 0u;
            if (sb >= TOPK && sn < TOPK) { shB = i; shAbove = sn; shNcand = sb; }
        }
        __syncthreads();
    }

    // ---- rare exact-refinement path (only if >CCAP ties in boundary bin) ----
    const bool refine = (shNcand > CCAP);
    if (refine) {
        for (int i = t; i < 4096; i += 1024) hist[i] = 0u;
        __syncthreads();
        const unsigned Bv = (unsigned)shB;
        for (int i = t; i < N4; i += 1024) {
            float4 v = xc4[i];
            float a[4] = {v.x, v.y, v.z, v.w};
            #pragma unroll
            for (int c_ = 0; c_ < 4; ++c_) {
                unsigned vk = fkey(a[c_]);
                if ((vk >> 20) == Bv) atomicAdd(&hist[(vk >> 8) & 0xFFFu], 1u);
            }
        }
        __syncthreads();
        if (t == 0) {
            unsigned need = TOPK - shAbove, cum = 0u;
            int b2 = 4095;
            for (; b2 >= 0; --b2) { cum += hist[b2]; if (cum >= need) break; }
            shB2 = (b2 < 0) ? 0 : b2;
        }
        __syncthreads();
    }

    // ---- pass 2: collect candidate keys (global index = c*HW + local) ----
    {
        const unsigned Bv = (unsigned)shB;
        const unsigned B2v = refine ? (unsigned)shB2 : 0u;
        const unsigned cbase = (unsigned)c << 16;   // c * HW
        for (int i = t; i < N4; i += 1024) {
            float4 v = xc4[i];
            float a[4] = {v.x, v.y, v.z, v.w};
            #pragma unroll
            for (int c_ = 0; c_ < 4; ++c_) {
                unsigned vk = fkey(a[c_]);
                unsigned bin = vk >> 20;
                bool q = refine ? (bin > Bv || (bin == Bv && ((vk >> 8) & 0xFFFu) >= B2v))
                                : (bin >= Bv);
                if (q) {
                    unsigned pos = atomicAdd(&shNc, 1u);
                    if (pos < CCAP)
                        cand[pos] = ((unsigned long long)vk << 32) |
                                    (unsigned)~(cbase | (unsigned)(i * 4 + c_));
                }
            }
        }
        __syncthreads();
    }

    unsigned nc = shNc; if (nc > CCAP) nc = CCAP;   // nc >= 100 by construction

    // ---- pad to pow2 and bitonic sort descending ----
    int P = 128; while (P < (int)nc) P <<= 1;       // <= 2048
    for (int i = (int)nc + t; i < P; i += 1024) cand[i] = 0ull;
    __syncthreads();
    for (int k = 2; k <= P; k <<= 1) {
        for (int j = k >> 1; j > 0; j >>= 1) {
            for (int i = t; i < P; i += 1024) {
                int ixj = i ^ j;
                if (ixj > i) {
                    unsigned long long a = cand[i], c2 = cand[ixj];
                    bool sw = ((i & k) == 0) ? (a < c2) : (a > c2);
                    if (sw) { cand[i] = c2; cand[ixj] = a; }
                }
            }
            __syncthreads();
        }
    }

    if (t < TOPK) ws[(size_t)bid * TOPK + t] = cand[t];
}

// ---------------------------------------------------------------------------
// Kernel 2 (new): per batch — merge 3x100 keys per slice, decode, then
// fully in-register single-wave soft-NMS (zero barriers in the NMS loop).
// 32 blocks x 256 threads; wave 0 does the NMS after the last barrier.
// ---------------------------------------------------------------------------
__global__ __launch_bounds__(256) void knms2(const float* __restrict__ x,
                                             const unsigned long long* __restrict__ ws,
                                             float* __restrict__ out) {
    __shared__ unsigned long long skey[512];
    __shared__ float bxs[NBOX][4];
    __shared__ float scs[NBOX];
    __shared__ float cl[NBOX];

    const int b = blockIdx.x, t = threadIdx.x;

    // ---- phase A: per slice, sort the 300-key union and decode top-100 ----
    for (int s = 0; s < 2; ++s) {
        const int slice = 2 * b + s;
        for (int i = t; i < 512; i += 256)
            skey[i] = (i < 3 * TOPK) ? ws[(size_t)slice * 3 * TOPK + i] : 0ull;
        __syncthreads();
        for (int k = 2; k <= 512; k <<= 1) {
            for (int j = k >> 1; j > 0; j >>= 1) {
                for (int i = t; i < 512; i += 256) {
                    int ixj = i ^ j;
                    if (ixj > i) {
                        unsigned long long a = skey[i], c2 = skey[ixj];
                        bool sw = ((i & k) == 0) ? (a < c2) : (a > c2);
                        if (sw) { skey[i] = c2; skey[ixj] = a; }
                    }
                }
                __syncthreads();
            }
        }
        if (t < TOPK) {
            unsigned long long K = skey[t];
            unsigned vk = (unsigned)(K >> 32);
            unsigned idx = ~((unsigned)K);
            unsigned u = (vk & 0x80000000u) ? (vk & 0x7FFFFFFFu) : ~vk;
            float z = __uint_as_float(u);           // exact original logit
            int c = (int)(idx >> 16);               // HW == 2^16
            int rem = (int)(idx & 0xFFFFu);
            const float* xb = x + (size_t)slice * SLICE_STRIDE;
            float ysf = (float)(rem >> 8);
            float xsf = (float)(rem & 255);
            float offx = xb[3 * HW + rem];
            float offy = xb[4 * HW + rem];
            float bw = xb[5 * HW + rem] * 4.0f;
            float bh = xb[6 * HW + rem] * 4.0f;
            float cx = (xsf + offx) * 4.0f;
            float cy = (ysf + offy) * 4.0f;
            int slot = s * TOPK + t;
            bxs[slot][0] = cx - bw * 0.5f;
            bxs[slot][1] = cy - bh * 0.5f;
            bxs[slot][2] = cx + bw * 0.5f;
            bxs[slot][3] = cy + bh * 0.5f;
            float sg = 1.0f / (1.0f + expf(-z));
            scs[slot] = (sg > 0.1f) ? sg : 0.0f;
            cl[slot] = (float)c;
        }
        __syncthreads();
    }

    // ---- phase B: wave 0 only, register-resident soft-NMS, no barriers ----
    if (t < 64) {
        float X1[4], Y1[4], X2[4], Y2[4], SC[4], CLs[4];
        #pragma unroll
        for (int sl = 0; sl < 4; ++sl) {
            int p = sl * 64 + t;
            int q = (p < NBOX) ? p : 0;
            X1[sl] = bxs[q][0]; Y1[sl] = bxs[q][1];
            X2[sl] = bxs[q][2]; Y2[sl] = bxs[q][3];
            SC[sl] = scs[q];    CLs[sl] = cl[q];
        }

        // initial argmax over p in [0, NBOX): key = (score_bits<<32) | ~p
        unsigned long long kmax;
        {
            unsigned long long local = 0ull;
            #pragma unroll
            for (int sl = 0; sl < 4; ++sl) {
                int p = sl * 64 + t;
                if (p < NBOX) {
                    unsigned long long k =
                        ((unsigned long long)__float_as_uint(SC[sl]) << 32) |
                        (unsigned)~(unsigned)p;
                    if (k > local) local = k;
                }
            }
            #pragma unroll
            for (int off = 32; off > 0; off >>= 1) {
                unsigned long long o = __shfl_xor(local, off);
                if (o > local) local = o;
            }
            kmax = local;
        }

        for (int i = 0; i < NBOX; ++i) {
            int m = (int)(~((unsigned)kmax));       // first-occurrence max pos >= i
            int lane_m = m & 63, slot_m = m >> 6;
            int lane_i = i & 63, slot_i = i >> 6;

            // gather box m (becomes position i) and old box i (goes to m)
            float mx1 = __shfl(sel4(X1, slot_m), lane_m);
            float my1 = __shfl(sel4(Y1, slot_m), lane_m);
            float mx2 = __shfl(sel4(X2, slot_m), lane_m);
            float my2 = __shfl(sel4(Y2, slot_m), lane_m);
            float mcl = __shfl(sel4(CLs, slot_m), lane_m);
            float msc = __uint_as_float((unsigned)(kmax >> 32));
            float ix1 = __shfl(sel4(X1, slot_i), lane_i);
            float iy1 = __shfl(sel4(Y1, slot_i), lane_i);
            float ix2 = __shfl(sel4(X2, slot_i), lane_i);
            float iy2 = __shfl(sel4(Y2, slot_i), lane_i);
            float icl = __shfl(sel4(CLs, slot_i), lane_i);
            float isc = __shfl(sel4(SC, slot_i), lane_i);

            // physical swap (constant-index predicated register writes)
            #pragma unroll
            for (int sl = 0; sl < 4; ++sl) {
                if (t == lane_i && sl == slot_i) {
                    X1[sl] = mx1; Y1[sl] = my1; X2[sl] = mx2; Y2[sl] = my2;
                    SC[sl] = msc; CLs[sl] = mcl;
                }
                if (t == lane_m && sl == slot_m) {
                    X1[sl] = ix1; Y1[sl] = iy1; X2[sl] = ix2; Y2[sl] = iy2;
                    SC[sl] = isc; CLs[sl] = icl;
                }
            }

            // fused gaussian decay + argmax for next round (p > i)
            float area_i = (mx2 - mx1 + 1.0f) * (my2 - my1 + 1.0f);
            unsigned long long local = 0ull;
            #pragma unroll
            for (int sl = 0; sl < 4; ++sl) {
                int p = sl * 64 + t;
                if (p > i && p < NBOX) {
                    float x1 = X1[sl], y1 = Y1[sl], x2 = X2[sl], y2 = Y2[sl];
                    float areas = (x2 - x1 + 1.0f) * (y2 - y1 + 1.0f);
                    float xx1 = fmaxf(mx1, x1);
                    float yy1 = fmaxf(my1, y1);
                    float xx2 = fminf(mx2, x2);
                    float yy2 = fminf(my2, y2);
                    float inter = fmaxf(0.0f, xx2 - xx1 + 1.0f) *
                                  fmaxf(0.0f, yy2 - yy1 + 1.0f);
                    float iou = inter / (area_i + areas - inter);
                    float w = expf(-(iou * iou) / 0.5f);
                    float ns = w * SC[sl];
                    SC[sl] = ns;
                    unsigned long long k =
                        ((unsigned long long)__float_as_uint(ns) << 32) |
                        (unsigned)~(unsigned)p;
                    if (k > local) local = k;
                }
            }
            #pragma unroll
            for (int off = 32; off > 0; off >>= 1) {
                unsigned long long o = __shfl_xor(local, off);
                if (o > local) local = o;
            }
            kmax = local;
        }

        // ---- write outputs [boxes, cls, scores, keep] ----
        float* ob  = out + (size_t)b * NBOX * 4;
        float* oc  = out + (size_t)NBATCH * NBOX * 4 + b * NBOX;
        float* os  = out + (size_t)NBATCH * NBOX * 5 + b * NBOX;
        float* okp = out + (size_t)NBATCH * NBOX * 6 + b * NBOX;
        #pragma unroll
        for (int sl = 0; sl < 4; ++sl) {
            int p = sl * 64 + t;
            if (p < NBOX) {
                ob[p * 4 + 0] = X1[sl];
                ob[p * 4 + 1] = Y1[sl];
                ob[p * 4 + 2] = X2[sl];
                ob[p * 4 + 3] = Y2[sl];
                oc[p]  = CLs[sl];
                os[p]  = SC[sl];
                okp[p] = (SC[sl] > 0.1f) ? 1.0f : 0.0f;
            }
        }
    }
}

// ===========================================================================
// FALLBACK PATH (round-2 verified kernels, verbatim) — used if ws too small
// ===========================================================================
__global__ __launch_bounds__(1024) void ktopk(const float* __restrict__ x,
                                              float* __restrict__ out) {
    __shared__ unsigned hist[4096];
    __shared__ unsigned long long cand[CAP];
    __shared__ int shB, shB2;
    __shared__ unsigned shAbove, shNcand, shNc;

    const int slice = blockIdx.x;
    const int b = slice >> 1, s = slice & 1;
    const int t = threadIdx.x;
    const float* xb = x + (size_t)slice * SLICE_STRIDE;
    const float4* xb4 = (const float4*)xb;
    const int N4 = HM / 4;

    if (t == 0) { shB = 0; shB2 = 0; shAbove = 0u; shNcand = 0u; shNc = 0u; }
    for (int i = t; i < 4096; i += 1024) hist[i] = 0u;
    __syncthreads();

    for (int i = t; i < N4; i += 1024) {
        float4 v = xb4[i];
        float a[4] = {v.x, v.y, v.z, v.w};
        #pragma unroll
        for (int c_ = 0; c_ < 4; ++c_) {
            unsigned vk = fkey(a[c_]);
            atomicAdd(&hist[vk >> 20], 1u);
        }
    }
    __syncthreads();

    {
        unsigned* tmp = (unsigned*)cand;
        unsigned* src = hist;
        unsigned* dst = tmp;
        for (int d = 1; d < 4096; d <<= 1) {
            for (int i = t; i < 4096; i += 1024) {
                unsigned v = src[i];
                if (i + d < 4096) v += src[i + d];
                dst[i] = v;
            }
            __syncthreads();
            unsigned* sw = src; src = dst; dst = sw;
        }
        for (int i = t; i < 4096; i += 1024) {
            unsigned sb = src[i];
            unsigned sn = (i < 4095) ? src[i + 1] : 0u;
            if (sb >= TOPK && sn < TOPK) { shB = i; shAbove = sn; shNcand = sb; }
        }
        __syncthreads();
    }

    const bool refine = (shNcand > CAP);
    if (refine) {
        for (int i = t; i < 4096; i += 1024) hist[i] = 0u;
        __syncthreads();
        const unsigned Bv = (unsigned)shB;
        for (int i = t; i < N4; i += 1024) {
            float4 v = xb4[i];
            float a[4] = {v.x, v.y, v.z, v.w};
            #pragma unroll
            for (int c_ = 0; c_ < 4; ++c_) {
                unsigned vk = fkey(a[c_]);
                if ((vk >> 20) == Bv) atomicAdd(&hist[(vk >> 8) & 0xFFFu], 1u);
            }
        }
        __syncthreads();
        if (t == 0) {
            unsigned need = TOPK - shAbove, cum = 0u;
            int b2 = 4095;
            for (; b2 >= 0; --b2) { cum += hist[b2]; if (cum >= need) break; }
            shB2 = (b2 < 0) ? 0 : b2;
            shNcand = shAbove + cum;
        }
        __syncthreads();
    }

    {
        const unsigned Bv = (unsigned)shB;
        const unsigned B2v = refine ? (unsigned)shB2 : 0u;
        for (int i = t; i < N4; i += 1024) {
            float4 v = xb4[i];
            float a[4] = {v.x, v.y, v.z, v.w};
            #pragma unroll
            for (int c_ = 0; c_ < 4; ++c_) {
                unsigned vk = fkey(a[c_]);
                unsigned bin = vk >> 20;
                bool q = refine ? (bin > Bv || (bin == Bv && ((vk >> 8) & 0xFFFu) >= B2v))
                                : (bin >= Bv);
                if (q) {
                    unsigned pos = atomicAdd(&shNc, 1u);
                    if (pos < CAP)
                        cand[pos] = ((unsigned long long)vk << 32) |
                                    (unsigned)~(unsigned)(i * 4 + c_);
                }
            }
        }
        __syncthreads();
    }

    unsigned nc = shNc; if (nc > CAP) nc = CAP;
    int P = 128; while (P < (int)nc) P <<= 1;
    for (int i = (int)nc + t; i < P; i += 1024) cand[i] = 0ull;
    __syncthreads();
    for (int k = 2; k <= P; k <<= 1) {
        for (int j = k >> 1; j > 0; j >>= 1) {
            for (int i = t; i < P; i += 1024) {
                int ixj = i ^ j;
                if (ixj > i) {
                    unsigned long long a = cand[i], c2 = cand[ixj];
                    bool sw = ((i & k) == 0) ? (a < c2) : (a > c2);
                    if (sw) { cand[i] = c2; cand[ixj] = a; }
                }
            }
            __syncthreads();
        }
    }

    if (t < TOPK) {
        unsigned long long K = cand[t];
        unsigned vk = (unsigned)(K >> 32);
        unsigned idx = ~((unsigned)K);
        unsigned u = (vk & 0x80000000u) ? (vk & 0x7FFFFFFFu) : ~vk;
        float z = __uint_as_float(u);
        int c = (int)(idx >> 16);
        int rem = (int)(idx & 0xFFFFu);
        float ysf = (float)(rem >> 8);
        float xsf = (float)(rem & 255);
        float offx = xb[3 * HW + rem];
        float offy = xb[4 * HW + rem];
        float bw = xb[5 * HW + rem] * 4.0f;
        float bh = xb[6 * HW + rem] * 4.0f;
        float cx = (xsf + offx) * 4.0f;
        float cy = (ysf + offy) * 4.0f;
        int slot = s * TOPK + t;
        float* ob = out + (size_t)b * NBOX * 4;
        float* oc = out + (size_t)NBATCH * NBOX * 4 + b * NBOX;
        float* os = out + (size_t)NBATCH * NBOX * 5 + b * NBOX;
        ob[slot * 4 + 0] = cx - bw * 0.5f;
        ob[slot * 4 + 1] = cy - bh * 0.5f;
        ob[slot * 4 + 2] = cx + bw * 0.5f;
        ob[slot * 4 + 3] = cy + bh * 0.5f;
        float sg = 1.0f / (1.0f + expf(-z));
        os[slot] = (sg > 0.1f) ? sg : 0.0f;
        oc[slot] = (float)c;
    }
}

__global__ __launch_bounds__(64) void knms(float* __restrict__ out) {
    __shared__ float bxs[NBOX][4];
    __shared__ float scs[NBOX];
    __shared__ float cl[NBOX];

    const int b = blockIdx.x, t = threadIdx.x;
    float* ob  = out + (size_t)b * NBOX * 4;
    float* oc  = out + (size_t)NBATCH * NBOX * 4 + b * NBOX;
    float* os  = out + (size_t)NBATCH * NBOX * 5 + b * NBOX;
    float* okp = out + (size_t)NBATCH * NBOX * 6 + b * NBOX;

    for (int p = t; p < NBOX; p += 64) {
        bxs[p][0] = ob[p * 4 + 0];
        bxs[p][1] = ob[p * 4 + 1];
        bxs[p][2] = ob[p * 4 + 2];
        bxs[p][3] = ob[p * 4 + 3];
        scs[p] = os[p];
        cl[p]  = oc[p];
    }
    __syncthreads();

    unsigned long long local = 0ull;
    for (int p = t; p < NBOX; p += 64) {
        unsigned long long k =
            ((unsigned long long)__float_as_uint(scs[p]) << 32) | (unsigned)~(unsigned)p;
        if (k > local) local = k;
    }
    #pragma unroll
    for (int off = 32; off > 0; off >>= 1) {
        unsigned long long o = __shfl_xor(local, off);
        if (o > local) local = o;
    }
    unsigned long long kmax = local;

    for (int i = 0; i < NBOX; ++i) {
        int m = (int)(~((unsigned)kmax));
        if (t == 0 && m != i) {
            #pragma unroll
            for (int k = 0; k < 4; ++k) {
                float tmp = bxs[i][k]; bxs[i][k] = bxs[m][k]; bxs[m][k] = tmp;
            }
            float ts = scs[i]; scs[i] = scs[m]; scs[m] = ts;
            float tc = cl[i];  cl[i]  = cl[m];  cl[m]  = tc;
        }
        __syncthreads();

        float b0 = bxs[i][0], b1 = bxs[i][1], b2 = bxs[i][2], b3 = bxs[i][3];
        float area_i = (b2 - b0 + 1.0f) * (b3 - b1 + 1.0f);

        local = 0ull;
        for (int p = i + 1 + t; p < NBOX; p += 64) {
            float x1 = bxs[p][0], y1 = bxs[p][1], x2 = bxs[p][2], y2 = bxs[p][3];
            float areas = (x2 - x1 + 1.0f) * (y2 - y1 + 1.0f);
            float xx1 = fmaxf(b0, x1);
            float yy1 = fmaxf(b1, y1);
            float xx2 = fminf(b2, x2);
            float yy2 = fminf(b3, y2);
            float inter = fmaxf(0.0f, xx2 - xx1 + 1.0f) * fmaxf(0.0f, yy2 - yy1 + 1.0f);
            float iou = inter / (area_i + areas - inter);
            float w = expf(-(iou * iou) / 0.5f);
            float ns = w * scs[p];
            scs[p] = ns;
            unsigned long long k =
                ((unsigned long long)__float_as_uint(ns) << 32) | (unsigned)~(unsigned)p;
            if (k > local) local = k;
        }
        __syncthreads();
        #pragma unroll
        for (int off = 32; off > 0; off >>= 1) {
            unsigned long long o = __shfl_xor(local, off);
            if (o > local) local = o;
        }
        kmax = local;
    }
    __syncthreads();

    for (int p = t; p < NBOX; p += 64) {
        ob[p * 4 + 0] = bxs[p][0];
        ob[p * 4 + 1] = bxs[p][1];
        ob[p * 4 + 2] = bxs[p][2];
        ob[p * 4 + 3] = bxs[p][3];
        oc[p]  = cl[p];
        os[p]  = scs[p];
        okp[p] = (scs[p] > 0.1f) ? 1.0f : 0.0f;
    }
}

extern "C" void kernel_launch(void* const* d_in, const int* in_sizes, int n_in,
                              void* d_out, int out_size, void* d_ws, size_t ws_size,
                              hipStream_t stream) {
    const float* x = (const float*)d_in[0];
    float* out = (float*)d_out;
    if (d_ws != nullptr && ws_size >= WS_NEED) {
        kcls<<<192, 1024, 0, stream>>>(x, (unsigned long long*)d_ws);
        knms2<<<NBATCH, 256, 0, stream>>>(x, (const unsigned long long*)d_ws, out);
    } else {
        ktopk<<<2 * NBATCH, 1024, 0, stream>>>(x, out);
        knms<<<NBATCH, 64, 0, stream>>>(out);
    }
}

// Round 4
// 358.250 us; speedup vs baseline: 1.2446x; 1.2446x over previous
//
#include <hip/hip_runtime.h>
#include <math.h>

#define TOPK 100
#define HW 65536                   // 256*256
#define SLICE_STRIDE (7*HW)        // 458752
#define NBATCH 32
#define NBOX 200
#define HM (3*HW)                  // 196608 heatmap elems per slice
#define CAP 4096                   // candidate cap (fallback per-slice path)
#define CCAP 2048                  // candidate cap (per-class path)
#define WS_NEED ((size_t)(192 * TOPK * 8))

// Order-preserving float->uint key: f1 > f2  <=>  key(f1) > key(f2)
__device__ __forceinline__ unsigned fkey(float f) {
    unsigned u = __float_as_uint(f);
    return (u & 0x80000000u) ? ~u : (u | 0x80000000u);
}

// ---------------------------------------------------------------------------
// Wave64 u32 max-reduce. DPP version: ~12 VALU ops (vs ~12 dependent
// ds_bpermute for the shuffle tree — the round-3 regression). Identity is 0,
// so it is robust to either bound_ctrl convention (invalid lanes -> old=self
// or 0; both are identities for non-negative max). Result uniform.
// ---------------------------------------------------------------------------
#if defined(__has_builtin) && __has_builtin(__builtin_amdgcn_update_dpp)
__device__ __forceinline__ unsigned wave_umax(unsigned x) {
    unsigned t;
    t = (unsigned)__builtin_amdgcn_update_dpp((int)x, (int)x, 0x111, 0xF, 0xF, false); // row_shr:1
    x = x > t ? x : t;
    t = (unsigned)__builtin_amdgcn_update_dpp((int)x, (int)x, 0x112, 0xF, 0xF, false); // row_shr:2
    x = x > t ? x : t;
    t = (unsigned)__builtin_amdgcn_update_dpp((int)x, (int)x, 0x114, 0xF, 0xF, false); // row_shr:4
    x = x > t ? x : t;
    t = (unsigned)__builtin_amdgcn_update_dpp((int)x, (int)x, 0x118, 0xF, 0xF, false); // row_shr:8
    x = x > t ? x : t;
    t = (unsigned)__builtin_amdgcn_update_dpp((int)x, (int)x, 0x142, 0xF, 0xF, false); // row_bcast:15
    x = x > t ? x : t;
    t = (unsigned)__builtin_amdgcn_update_dpp((int)x, (int)x, 0x143, 0xF, 0xF, false); // row_bcast:31
    x = x > t ? x : t;
    return (unsigned)__builtin_amdgcn_readlane((int)x, 63);
}
#else
__device__ __forceinline__ unsigned wave_umax(unsigned x) {
    #pragma unroll
    for (int off = 32; off > 0; off >>= 1) {
        unsigned o = (unsigned)__shfl_xor((int)x, off);
        x = x > o ? x : o;
    }
    return x;
}
#endif

// ===========================================================================
// Kernel 1: exact top-100 per (slice, class) channel — VERBATIM from the
// round-3 passing kernel. 192 blocks x 1024 threads. Keys carry the GLOBAL
// index (c*HW + rem) so merging preserves the verified ordering.
// ===========================================================================
__global__ __launch_bounds__(1024) void kcls(const float* __restrict__ x,
                                             unsigned long long* __restrict__ ws) {
    __shared__ unsigned hist[4096];                 // 16 KB
    __shared__ unsigned long long cand[CCAP];       // 16 KB (aliased as scan tmp)
    __shared__ int shB, shB2;
    __shared__ unsigned shAbove, shNcand, shNc;

    const int bid = blockIdx.x;
    const int slice = bid / 3, c = bid % 3;
    const int t = threadIdx.x;
    const float* xc = x + (size_t)slice * SLICE_STRIDE + (size_t)c * HW;
    const float4* xc4 = (const float4*)xc;
    const int N4 = HW / 4;                          // 16384

    if (t == 0) { shB = 0; shB2 = 0; shAbove = 0u; shNcand = 0u; shNc = 0u; }
    for (int i = t; i < 4096; i += 1024) hist[i] = 0u;
    __syncthreads();

    for (int i = t; i < N4; i += 1024) {
        float4 v = xc4[i];
        float a[4] = {v.x, v.y, v.z, v.w};
        #pragma unroll
        for (int c_ = 0; c_ < 4; ++c_) {
            unsigned vk = fkey(a[c_]);
            atomicAdd(&hist[vk >> 20], 1u);
        }
    }
    __syncthreads();

    {
        unsigned* tmp = (unsigned*)cand;
        unsigned* src = hist;
        unsigned* dst = tmp;
        for (int d = 1; d < 4096; d <<= 1) {
            for (int i = t; i < 4096; i += 1024) {
                unsigned v = src[i];
                if (i + d < 4096) v += src[i + d];
                dst[i] = v;
            }
            __syncthreads();
            unsigned* sw = src; src = dst; dst = sw;
        }
        for (int i = t; i < 4096; i += 1024) {
            unsigned sb = src[i];
            unsigned sn = (i < 4095) ? src[i + 1] : 0u;
            if (sb >= TOPK && sn < TOPK) { shB = i; shAbove = sn; shNcand = sb; }
        }
        __syncthreads();
    }

    const bool refine = (shNcand > CCAP);
    if (refine) {
        for (int i = t; i < 4096; i += 1024) hist[i] = 0u;
        __syncthreads();
        const unsigned Bv = (unsigned)shB;
        for (int i = t; i < N4; i += 1024) {
            float4 v = xc4[i];
            float a[4] = {v.x, v.y, v.z, v.w};
            #pragma unroll
            for (int c_ = 0; c_ < 4; ++c_) {
                unsigned vk = fkey(a[c_]);
                if ((vk >> 20) == Bv) atomicAdd(&hist[(vk >> 8) & 0xFFFu], 1u);
            }
        }
        __syncthreads();
        if (t == 0) {
            unsigned need = TOPK - shAbove, cum = 0u;
            int b2 = 4095;
            for (; b2 >= 0; --b2) { cum += hist[b2]; if (cum >= need) break; }
            shB2 = (b2 < 0) ? 0 : b2;
        }
        __syncthreads();
    }

    {
        const unsigned Bv = (unsigned)shB;
        const unsigned B2v = refine ? (unsigned)shB2 : 0u;
        const unsigned cbase = (unsigned)c << 16;   // c * HW
        for (int i = t; i < N4; i += 1024) {
            float4 v = xc4[i];
            float a[4] = {v.x, v.y, v.z, v.w};
            #pragma unroll
            for (int c_ = 0; c_ < 4; ++c_) {
                unsigned vk = fkey(a[c_]);
                unsigned bin = vk >> 20;
                bool q = refine ? (bin > Bv || (bin == Bv && ((vk >> 8) & 0xFFFu) >= B2v))
                                : (bin >= Bv);
                if (q) {
                    unsigned pos = atomicAdd(&shNc, 1u);
                    if (pos < CCAP)
                        cand[pos] = ((unsigned long long)vk << 32) |
                                    (unsigned)~(cbase | (unsigned)(i * 4 + c_));
                }
            }
        }
        __syncthreads();
    }

    unsigned nc = shNc; if (nc > CCAP) nc = CCAP;

    int P = 128; while (P < (int)nc) P <<= 1;       // <= 2048
    for (int i = (int)nc + t; i < P; i += 1024) cand[i] = 0ull;
    __syncthreads();
    for (int k = 2; k <= P; k <<= 1) {
        for (int j = k >> 1; j > 0; j >>= 1) {
            for (int i = t; i < P; i += 1024) {
                int ixj = i ^ j;
                if (ixj > i) {
                    unsigned long long a = cand[i], c2 = cand[ixj];
                    bool sw = ((i & k) == 0) ? (a < c2) : (a > c2);
                    if (sw) { cand[i] = c2; cand[ixj] = a; }
                }
            }
            __syncthreads();
        }
    }

    if (t < TOPK) ws[(size_t)bid * TOPK + t] = cand[t];
}

// ===========================================================================
// Kernel 2: merge+decode (phase A, verbatim structure from round 3) then
// virtual-position soft-NMS (phase B): no physical swap, no shuffles in the
// round loop — DPP reduces + one uniform ds_read_b128 per round.
// ===========================================================================
__global__ __launch_bounds__(256) void knms3(const float* __restrict__ x,
                                             const unsigned long long* __restrict__ ws,
                                             float* __restrict__ out) {
    __shared__ unsigned long long skey[512];
    __shared__ float4 bxs4[NBOX];
    __shared__ float scs[NBOX];
    __shared__ float cl[NBOX];

    const int b = blockIdx.x, t = threadIdx.x;

    // ---- phase A: per slice, sort the 300-key union and decode top-100 ----
    for (int s = 0; s < 2; ++s) {
        const int slice = 2 * b + s;
        for (int i = t; i < 512; i += 256)
            skey[i] = (i < 3 * TOPK) ? ws[(size_t)slice * 3 * TOPK + i] : 0ull;
        __syncthreads();
        for (int k = 2; k <= 512; k <<= 1) {
            for (int j = k >> 1; j > 0; j >>= 1) {
                for (int i = t; i < 512; i += 256) {
                    int ixj = i ^ j;
                    if (ixj > i) {
                        unsigned long long a = skey[i], c2 = skey[ixj];
                        bool sw = ((i & k) == 0) ? (a < c2) : (a > c2);
                        if (sw) { skey[i] = c2; skey[ixj] = a; }
                    }
                }
                __syncthreads();
            }
        }
        if (t < TOPK) {
            unsigned long long K = skey[t];
            unsigned vk = (unsigned)(K >> 32);
            unsigned idx = ~((unsigned)K);
            unsigned u = (vk & 0x80000000u) ? (vk & 0x7FFFFFFFu) : ~vk;
            float z = __uint_as_float(u);           // exact original logit
            int c = (int)(idx >> 16);               // HW == 2^16
            int rem = (int)(idx & 0xFFFFu);
            const float* xb = x + (size_t)slice * SLICE_STRIDE;
            float ysf = (float)(rem >> 8);
            float xsf = (float)(rem & 255);
            float offx = xb[3 * HW + rem];
            float offy = xb[4 * HW + rem];
            float bw = xb[5 * HW + rem] * 4.0f;
            float bh = xb[6 * HW + rem] * 4.0f;
            float cx = (xsf + offx) * 4.0f;
            float cy = (ysf + offy) * 4.0f;
            int slot = s * TOPK + t;
            bxs4[slot] = make_float4(cx - bw * 0.5f, cy - bh * 0.5f,
                                     cx + bw * 0.5f, cy + bh * 0.5f);
            float sg = 1.0f / (1.0f + expf(-z));
            scs[slot] = (sg > 0.1f) ? sg : 0.0f;
            cl[slot] = (float)c;
        }
        __syncthreads();
    }

    // ---- phase B: wave 0, virtual-position soft-NMS ----
    // Boxes immutable; only cpos permutes and scores decay. Selection key
    // (score bits desc, current pos asc) == verified round-2 comparator.
    if (t < 64) {
        float X1[4], Y1[4], X2[4], Y2[4], SC[4], CL4[4];
        unsigned CP[4];
        #pragma unroll
        for (int sl = 0; sl < 4; ++sl) {
            int p = sl * 64 + t;
            int q = (p < NBOX) ? p : 0;
            float4 bb = bxs4[q];
            X1[sl] = bb.x; Y1[sl] = bb.y; X2[sl] = bb.z; Y2[sl] = bb.w;
            SC[sl] = (p < NBOX) ? scs[q] : 0.0f;    // phantoms: score 0, inert
            CL4[sl] = cl[q];
            CP[sl] = (unsigned)p;                   // phantoms: cpos 200..255
        }

        for (int i = 0; i < NBOX; ++i) {
            const unsigned ui = (unsigned)i;
            // phase 1: max score bits among active real boxes (cpos >= i)
            unsigned lb = 0u;
            #pragma unroll
            for (int sl = 0; sl < 4; ++sl) {
                int p = sl * 64 + t;
                unsigned bits = __float_as_uint(SC[sl]);
                bool act = (p < NBOX) && (CP[sl] >= ui);
                unsigned v = act ? bits : 0u;
                lb = lb > v ? lb : v;
            }
            unsigned smax = wave_umax(lb);

            // phase 2: among active & bits==smax, min cpos (tie impossible:
            // cpos unique). Encoded as max of ~((cpos<<8)|orig) -> also
            // recovers the winner's original slot for the pivot lookup.
            unsigned lc = 0u;
            #pragma unroll
            for (int sl = 0; sl < 4; ++sl) {
                int p = sl * 64 + t;
                bool sel = (p < NBOX) && (CP[sl] >= ui) &&
                           (__float_as_uint(SC[sl]) == smax);
                unsigned cd = ~((CP[sl] << 8) | (unsigned)p);
                unsigned v = sel ? cd : 0u;
                lc = lc > v ? lc : v;
            }
            unsigned win = ~wave_umax(lc);
            unsigned m = win >> 8;                  // current position of max
            unsigned worig = win & 0xFFu;           // original slot of max

            // pivot box: uniform LDS broadcast read (boxes immutable)
            float4 pv = bxs4[worig];
            float area_i = (pv.z - pv.x + 1.0f) * (pv.w - pv.y + 1.0f);

            // virtual swap: pos i <-> pos m
            #pragma unroll
            for (int sl = 0; sl < 4; ++sl) {
                unsigned cp = CP[sl];
                unsigned ncp = (cp == ui) ? m : cp;
                ncp = (cp == m) ? ui : ncp;
                CP[sl] = ncp;
            }

            // gaussian decay for current positions > i (formulas verbatim)
            #pragma unroll
            for (int sl = 0; sl < 4; ++sl) {
                int p = sl * 64 + t;
                if ((p < NBOX) && (CP[sl] > ui)) {
                    float x1 = X1[sl], y1 = Y1[sl], x2 = X2[sl], y2 = Y2[sl];
                    float areas = (x2 - x1 + 1.0f) * (y2 - y1 + 1.0f);
                    float xx1 = fmaxf(pv.x, x1);
                    float yy1 = fmaxf(pv.y, y1);
                    float xx2 = fminf(pv.z, x2);
                    float yy2 = fminf(pv.w, y2);
                    float inter = fmaxf(0.0f, xx2 - xx1 + 1.0f) *
                                  fmaxf(0.0f, yy2 - yy1 + 1.0f);
                    float iou = inter / (area_i + areas - inter);
                    float w = expf(-(iou * iou) / 0.5f);
                    SC[sl] = w * SC[sl];
                }
            }
        }

        // ---- write outputs: box with final cpos q lands at position q ----
        float* ob  = out + (size_t)b * NBOX * 4;
        float* oc  = out + (size_t)NBATCH * NBOX * 4 + b * NBOX;
        float* os  = out + (size_t)NBATCH * NBOX * 5 + b * NBOX;
        float* okp = out + (size_t)NBATCH * NBOX * 6 + b * NBOX;
        #pragma unroll
        for (int sl = 0; sl < 4; ++sl) {
            int p = sl * 64 + t;
            if (p < NBOX) {
                unsigned q = CP[sl];
                ob[q * 4 + 0] = X1[sl];
                ob[q * 4 + 1] = Y1[sl];
                ob[q * 4 + 2] = X2[sl];
                ob[q * 4 + 3] = Y2[sl];
                oc[q]  = CL4[sl];
                os[q]  = SC[sl];
                okp[q] = (SC[sl] > 0.1f) ? 1.0f : 0.0f;
            }
        }
    }
}

// ===========================================================================
// FALLBACK PATH (round-2 verified kernels, verbatim) — used if ws too small
// ===========================================================================
__global__ __launch_bounds__(1024) void ktopk(const float* __restrict__ x,
                                              float* __restrict__ out) {
    __shared__ unsigned hist[4096];
    __shared__ unsigned long long cand[CAP];
    __shared__ int shB, shB2;
    __shared__ unsigned shAbove, shNcand, shNc;

    const int slice = blockIdx.x;
    const int b = slice >> 1, s = slice & 1;
    const int t = threadIdx.x;
    const float* xb = x + (size_t)slice * SLICE_STRIDE;
    const float4* xb4 = (const float4*)xb;
    const int N4 = HM / 4;

    if (t == 0) { shB = 0; shB2 = 0; shAbove = 0u; shNcand = 0u; shNc = 0u; }
    for (int i = t; i < 4096; i += 1024) hist[i] = 0u;
    __syncthreads();

    for (int i = t; i < N4; i += 1024) {
        float4 v = xb4[i];
        float a[4] = {v.x, v.y, v.z, v.w};
        #pragma unroll
        for (int c_ = 0; c_ < 4; ++c_) {
            unsigned vk = fkey(a[c_]);
            atomicAdd(&hist[vk >> 20], 1u);
        }
    }
    __syncthreads();

    {
        unsigned* tmp = (unsigned*)cand;
        unsigned* src = hist;
        unsigned* dst = tmp;
        for (int d = 1; d < 4096; d <<= 1) {
            for (int i = t; i < 4096; i += 1024) {
                unsigned v = src[i];
                if (i + d < 4096) v += src[i + d];
                dst[i] = v;
            }
            __syncthreads();
            unsigned* sw = src; src = dst; dst = sw;
        }
        for (int i = t; i < 4096; i += 1024) {
            unsigned sb = src[i];
            unsigned sn = (i < 4095) ? src[i + 1] : 0u;
            if (sb >= TOPK && sn < TOPK) { shB = i; shAbove = sn; shNcand = sb; }
        }
        __syncthreads();
    }

    const bool refine = (shNcand > CAP);
    if (refine) {
        for (int i = t; i < 4096; i += 1024) hist[i] = 0u;
        __syncthreads();
        const unsigned Bv = (unsigned)shB;
        for (int i = t; i < N4; i += 1024) {
            float4 v = xb4[i];
            float a[4] = {v.x, v.y, v.z, v.w};
            #pragma unroll
            for (int c_ = 0; c_ < 4; ++c_) {
                unsigned vk = fkey(a[c_]);
                if ((vk >> 20) == Bv) atomicAdd(&hist[(vk >> 8) & 0xFFFu], 1u);
            }
        }
        __syncthreads();
        if (t == 0) {
            unsigned need = TOPK - shAbove, cum = 0u;
            int b2 = 4095;
            for (; b2 >= 0; --b2) { cum += hist[b2]; if (cum >= need) break; }
            shB2 = (b2 < 0) ? 0 : b2;
            shNcand = shAbove + cum;
        }
        __syncthreads();
    }

    {
        const unsigned Bv = (unsigned)shB;
        const unsigned B2v = refine ? (unsigned)shB2 : 0u;
        for (int i = t; i < N4; i += 1024) {
            float4 v = xb4[i];
            float a[4] = {v.x, v.y, v.z, v.w};
            #pragma unroll
            for (int c_ = 0; c_ < 4; ++c_) {
                unsigned vk = fkey(a[c_]);
                unsigned bin = vk >> 20;
                bool q = refine ? (bin > Bv || (bin == Bv && ((vk >> 8) & 0xFFFu) >= B2v))
                                : (bin >= Bv);
                if (q) {
                    unsigned pos = atomicAdd(&shNc, 1u);
                    if (pos < CAP)
                        cand[pos] = ((unsigned long long)vk << 32) |
                                    (unsigned)~(unsigned)(i * 4 + c_);
                }
            }
        }
        __syncthreads();
    }

    unsigned nc = shNc; if (nc > CAP) nc = CAP;
    int P = 128; while (P < (int)nc) P <<= 1;
    for (int i = (int)nc + t; i < P; i += 1024) cand[i] = 0ull;
    __syncthreads();
    for (int k = 2; k <= P; k <<= 1) {
        for (int j = k >> 1; j > 0; j >>= 1) {
            for (int i = t; i < P; i += 1024) {
                int ixj = i ^ j;
                if (ixj > i) {
                    unsigned long long a = cand[i], c2 = cand[ixj];
                    bool sw = ((i & k) == 0) ? (a < c2) : (a > c2);
                    if (sw) { cand[i] = c2; cand[ixj] = a; }
                }
            }
            __syncthreads();
        }
    }

    if (t < TOPK) {
        unsigned long long K = cand[t];
        unsigned vk = (unsigned)(K >> 32);
        unsigned idx = ~((unsigned)K);
        unsigned u = (vk & 0x80000000u) ? (vk & 0x7FFFFFFFu) : ~vk;
        float z = __uint_as_float(u);
        int c = (int)(idx >> 16);
        int rem = (int)(idx & 0xFFFFu);
        float ysf = (float)(rem >> 8);
        float xsf = (float)(rem & 255);
        float offx = xb[3 * HW + rem];
        float offy = xb[4 * HW + rem];
        float bw = xb[5 * HW + rem] * 4.0f;
        float bh = xb[6 * HW + rem] * 4.0f;
        float cx = (xsf + offx) * 4.0f;
        float cy = (ysf + offy) * 4.0f;
        int slot = s * TOPK + t;
        float* ob = out + (size_t)b * NBOX * 4;
        float* oc = out + (size_t)NBATCH * NBOX * 4 + b * NBOX;
        float* os = out + (size_t)NBATCH * NBOX * 5 + b * NBOX;
        ob[slot * 4 + 0] = cx - bw * 0.5f;
        ob[slot * 4 + 1] = cy - bh * 0.5f;
        ob[slot * 4 + 2] = cx + bw * 0.5f;
        ob[slot * 4 + 3] = cy + bh * 0.5f;
        float sg = 1.0f / (1.0f + expf(-z));
        os[slot] = (sg > 0.1f) ? sg : 0.0f;
        oc[slot] = (float)c;
    }
}

__global__ __launch_bounds__(64) void knms(float* __restrict__ out) {
    __shared__ float bxs[NBOX][4];
    __shared__ float scs[NBOX];
    __shared__ float cl[NBOX];

    const int b = blockIdx.x, t = threadIdx.x;
    float* ob  = out + (size_t)b * NBOX * 4;
    float* oc  = out + (size_t)NBATCH * NBOX * 4 + b * NBOX;
    float* os  = out + (size_t)NBATCH * NBOX * 5 + b * NBOX;
    float* okp = out + (size_t)NBATCH * NBOX * 6 + b * NBOX;

    for (int p = t; p < NBOX; p += 64) {
        bxs[p][0] = ob[p * 4 + 0];
        bxs[p][1] = ob[p * 4 + 1];
        bxs[p][2] = ob[p * 4 + 2];
        bxs[p][3] = ob[p * 4 + 3];
        scs[p] = os[p];
        cl[p]  = oc[p];
    }
    __syncthreads();

    unsigned long long local = 0ull;
    for (int p = t; p < NBOX; p += 64) {
        unsigned long long k =
            ((unsigned long long)__float_as_uint(scs[p]) << 32) | (unsigned)~(unsigned)p;
        if (k > local) local = k;
    }
    #pragma unroll
    for (int off = 32; off > 0; off >>= 1) {
        unsigned long long o = __shfl_xor(local, off);
        if (o > local) local = o;
    }
    unsigned long long kmax = local;

    for (int i = 0; i < NBOX; ++i) {
        int m = (int)(~((unsigned)kmax));
        if (t == 0 && m != i) {
            #pragma unroll
            for (int k = 0; k < 4; ++k) {
                float tmp = bxs[i][k]; bxs[i][k] = bxs[m][k]; bxs[m][k] = tmp;
            }
            float ts = scs[i]; scs[i] = scs[m]; scs[m] = ts;
            float tc = cl[i];  cl[i]  = cl[m];  cl[m]  = tc;
        }
        __syncthreads();

        float b0 = bxs[i][0], b1 = bxs[i][1], b2 = bxs[i][2], b3 = bxs[i][3];
        float area_i = (b2 - b0 + 1.0f) * (b3 - b1 + 1.0f);

        local = 0ull;
        for (int p = i + 1 + t; p < NBOX; p += 64) {
            float x1 = bxs[p][0], y1 = bxs[p][1], x2 = bxs[p][2], y2 = bxs[p][3];
            float areas = (x2 - x1 + 1.0f) * (y2 - y1 + 1.0f);
            float xx1 = fmaxf(b0, x1);
            float yy1 = fmaxf(b1, y1);
            float xx2 = fminf(b2, x2);
            float yy2 = fminf(b3, y2);
            float inter = fmaxf(0.0f, xx2 - xx1 + 1.0f) * fmaxf(0.0f, yy2 - yy1 + 1.0f);
            float iou = inter / (area_i + areas - inter);
            float w = expf(-(iou * iou) / 0.5f);
            float ns = w * scs[p];
            scs[p] = ns;
            unsigned long long k =
                ((unsigned long long)__float_as_uint(ns) << 32) | (unsigned)~(unsigned)p;
            if (k > local) local = k;
        }
        __syncthreads();
        #pragma unroll
        for (int off = 32; off > 0; off >>= 1) {
            unsigned long long o = __shfl_xor(local, off);
            if (o > local) local = o;
        }
        kmax = local;
    }
    __syncthreads();

    for (int p = t; p < NBOX; p += 64) {
        ob[p * 4 + 0] = bxs[p][0];
        ob[p * 4 + 1] = bxs[p][1];
        ob[p * 4 + 2] = bxs[p][2];
        ob[p * 4 + 3] = bxs[p][3];
        oc[p]  = cl[p];
        os[p]  = scs[p];
        okp[p] = (scs[p] > 0.1f) ? 1.0f : 0.0f;
    }
}

extern "C" void kernel_launch(void* const* d_in, const int* in_sizes, int n_in,
                              void* d_out, int out_size, void* d_ws, size_t ws_size,
                              hipStream_t stream) {
    const float* x = (const float*)d_in[0];
    float* out = (float*)d_out;
    if (d_ws != nullptr && ws_size >= WS_NEED) {
        kcls<<<192, 1024, 0, stream>>>(x, (unsigned long long*)d_ws);
        knms3<<<NBATCH, 256, 0, stream>>>(x, (const unsigned long long*)d_ws, out);
    } else {
        ktopk<<<2 * NBATCH, 1024, 0, stream>>>(x, out);
        knms<<<NBATCH, 64, 0, stream>>>(out);
    }
}

// Round 5
// 312.506 us; speedup vs baseline: 1.4268x; 1.1464x over previous
//
#include <hip/hip_runtime.h>
#include <math.h>

#define TOPK 100
#define HW 65536                   // 256*256
#define SLICE_STRIDE (7*HW)        // 458752
#define NBATCH 32
#define NBOX 200
#define HM (3*HW)                  // 196608 heatmap elems per slice
#define CAP 4096                   // candidate cap (old fallback per-slice path)
#define CCAP 2048                  // candidate cap (per-class path)
#define WS_NEED ((size_t)(192 * TOPK * 8))
#define TKEY 0xC0200000u           // fkey(2.5f): static collect threshold.
                                   // N(0,1): ~407+-20 cands/channel >= 2.5;
                                   // P(<100) ~ 15 sigma -> never; exact
                                   // histogram fallback guards correctness.

// Order-preserving float->uint key: f1 > f2  <=>  key(f1) > key(f2)
__device__ __forceinline__ unsigned fkey(float f) {
    unsigned u = __float_as_uint(f);
    return (u & 0x80000000u) ? ~u : (u | 0x80000000u);
}

// ---------------------------------------------------------------------------
// Wave64 u64 max-reduce via DPP (row_shr 1/2/4/8 + row_bcast 15/31, result in
// lane 63, broadcast via readlane). Same network as the round-4 verified
// 32-bit version; 64-bit op applied to (hi,lo) pairs moved with identical
// ctrl so pairs stay coherent. Identity 0; bound_ctrl=false keeps old=self
// on invalid lanes (idempotent for max).
// ---------------------------------------------------------------------------
#if defined(__has_builtin) && __has_builtin(__builtin_amdgcn_update_dpp)
#define DPP64_STEP(ctrl)                                                        \
    {                                                                           \
        unsigned lo = (unsigned)x, hi = (unsigned)(x >> 32);                    \
        unsigned olo = (unsigned)__builtin_amdgcn_update_dpp((int)lo, (int)lo,  \
                                                             (ctrl), 0xF, 0xF, false); \
        unsigned ohi = (unsigned)__builtin_amdgcn_update_dpp((int)hi, (int)hi,  \
                                                             (ctrl), 0xF, 0xF, false); \
        unsigned long long o = ((unsigned long long)ohi << 32) | olo;           \
        x = (o > x) ? o : x;                                                    \
    }
__device__ __forceinline__ unsigned long long wave_umax64(unsigned long long x) {
    DPP64_STEP(0x111)   // row_shr:1
    DPP64_STEP(0x112)   // row_shr:2
    DPP64_STEP(0x114)   // row_shr:4
    DPP64_STEP(0x118)   // row_shr:8
    DPP64_STEP(0x142)   // row_bcast:15
    DPP64_STEP(0x143)   // row_bcast:31
    unsigned rlo = (unsigned)__builtin_amdgcn_readlane((int)(unsigned)x, 63);
    unsigned rhi = (unsigned)__builtin_amdgcn_readlane((int)(unsigned)(x >> 32), 63);
    return ((unsigned long long)rhi << 32) | rlo;
}
#else
__device__ __forceinline__ unsigned long long wave_umax64(unsigned long long x) {
    #pragma unroll
    for (int off = 32; off > 0; off >>= 1) {
        unsigned long long o = __shfl_xor(x, off);
        if (o > x) x = o;
    }
    return x;
}
#endif

// ===========================================================================
// Kernel 1: exact top-100 per (slice, class). 192 blocks x 1024 threads.
// FAST PATH: one streaming pass collecting keys >= TKEY (no histogram, no
// scan, no second read). nc >= 100 proves top-100 is a subset of the
// collected set. FALLBACK (nc<100 or overflow): full round-4 verified
// histogram-threshold path, in-kernel.
// ===========================================================================
__global__ __launch_bounds__(1024) void kcol(const float* __restrict__ x,
                                             unsigned long long* __restrict__ ws) {
    __shared__ unsigned long long cand[CCAP];       // 16 KB (fallback: scan tmp)
    __shared__ unsigned hist[4096];                 // 16 KB (fallback only)
    __shared__ int shB, shB2;
    __shared__ unsigned shAbove, shNcand, shNc;

    const int bid = blockIdx.x;
    const int slice = bid / 3, c = bid % 3;
    const int t = threadIdx.x;
    const float* xc = x + (size_t)slice * SLICE_STRIDE + (size_t)c * HW;
    const float4* xc4 = (const float4*)xc;
    const int N4 = HW / 4;                          // 16384
    const unsigned cbase = (unsigned)c << 16;       // c * HW

    if (t == 0) shNc = 0u;
    __syncthreads();

    // ---- fast path: single streaming collect ----
    #pragma unroll 4
    for (int i = t; i < N4; i += 1024) {
        float4 v = xc4[i];
        float a[4] = {v.x, v.y, v.z, v.w};
        #pragma unroll
        for (int q = 0; q < 4; ++q) {
            unsigned vk = fkey(a[q]);
            if (vk >= TKEY) {
                unsigned pos = atomicAdd(&shNc, 1u);
                if (pos < CCAP)
                    cand[pos] = ((unsigned long long)vk << 32) |
                                (unsigned)~(cbase | (unsigned)(i * 4 + q));
            }
        }
    }
    __syncthreads();
    unsigned nc = shNc;

    if (nc < TOPK || nc > CCAP) {
        // ---- exact fallback: histogram threshold (round-4 verified) ----
        if (t == 0) { shB = 0; shB2 = 0; shAbove = 0u; shNcand = 0u; shNc = 0u; }
        for (int i = t; i < 4096; i += 1024) hist[i] = 0u;
        __syncthreads();
        for (int i = t; i < N4; i += 1024) {
            float4 v = xc4[i];
            float a[4] = {v.x, v.y, v.z, v.w};
            #pragma unroll
            for (int q = 0; q < 4; ++q) atomicAdd(&hist[fkey(a[q]) >> 20], 1u);
        }
        __syncthreads();
        {
            unsigned* tmp = (unsigned*)cand;
            unsigned* src = hist;
            unsigned* dst = tmp;
            for (int d = 1; d < 4096; d <<= 1) {
                for (int i = t; i < 4096; i += 1024) {
                    unsigned v2 = src[i];
                    if (i + d < 4096) v2 += src[i + d];
                    dst[i] = v2;
                }
                __syncthreads();
                unsigned* sw = src; src = dst; dst = sw;
            }
            for (int i = t; i < 4096; i += 1024) {
                unsigned sb = src[i];
                unsigned sn = (i < 4095) ? src[i + 1] : 0u;
                if (sb >= TOPK && sn < TOPK) { shB = i; shAbove = sn; shNcand = sb; }
            }
            __syncthreads();
        }
        const bool refine = (shNcand > CCAP);
        if (refine) {
            for (int i = t; i < 4096; i += 1024) hist[i] = 0u;
            __syncthreads();
            const unsigned Bv = (unsigned)shB;
            for (int i = t; i < N4; i += 1024) {
                float4 v = xc4[i];
                float a[4] = {v.x, v.y, v.z, v.w};
                #pragma unroll
                for (int q = 0; q < 4; ++q) {
                    unsigned vk = fkey(a[q]);
                    if ((vk >> 20) == Bv) atomicAdd(&hist[(vk >> 8) & 0xFFFu], 1u);
                }
            }
            __syncthreads();
            if (t == 0) {
                unsigned need = TOPK - shAbove, cum = 0u;
                int b2 = 4095;
                for (; b2 >= 0; --b2) { cum += hist[b2]; if (cum >= need) break; }
                shB2 = (b2 < 0) ? 0 : b2;
            }
            __syncthreads();
        }
        {
            const unsigned Bv = (unsigned)shB;
            const unsigned B2v = refine ? (unsigned)shB2 : 0u;
            for (int i = t; i < N4; i += 1024) {
                float4 v = xc4[i];
                float a[4] = {v.x, v.y, v.z, v.w};
                #pragma unroll
                for (int q = 0; q < 4; ++q) {
                    unsigned vk = fkey(a[q]);
                    unsigned bin = vk >> 20;
                    bool ok = refine ? (bin > Bv || (bin == Bv && ((vk >> 8) & 0xFFFu) >= B2v))
                                     : (bin >= Bv);
                    if (ok) {
                        unsigned pos = atomicAdd(&shNc, 1u);
                        if (pos < CCAP)
                            cand[pos] = ((unsigned long long)vk << 32) |
                                        (unsigned)~(cbase | (unsigned)(i * 4 + q));
                    }
                }
            }
            __syncthreads();
        }
        nc = shNc; if (nc > CCAP) nc = CCAP;
    }

    // ---- pad to pow2 and bitonic sort descending (64-bit keys) ----
    int P = 128; while (P < (int)nc) P <<= 1;       // <= 2048
    for (int i = (int)nc + t; i < P; i += 1024) cand[i] = 0ull;
    __syncthreads();
    for (int k = 2; k <= P; k <<= 1) {
        for (int j = k >> 1; j > 0; j >>= 1) {
            for (int i = t; i < P; i += 1024) {
                int ixj = i ^ j;
                if (ixj > i) {
                    unsigned long long a = cand[i], c2 = cand[ixj];
                    bool sw = ((i & k) == 0) ? (a < c2) : (a > c2);
                    if (sw) { cand[i] = c2; cand[ixj] = a; }
                }
            }
            __syncthreads();
        }
    }

    if (t < TOPK) ws[(size_t)bid * TOPK + t] = cand[t];
}

// ===========================================================================
// Kernel 2: 512 threads/block. Phase A: both slices' 300-key unions sorted
// IN PARALLEL (one half-block each) + decode. Phase B: wave-0 virtual-
// position soft-NMS with a single 64-bit DPP reduce per round (round-4's
// two-phase reduce collapsed) and hoisted round-invariant areas.
// ===========================================================================
__global__ __launch_bounds__(512) void knms4(const float* __restrict__ x,
                                             const unsigned long long* __restrict__ ws,
                                             float* __restrict__ out) {
    __shared__ unsigned long long skey[2][512];
    __shared__ float4 bxs4[NBOX];
    __shared__ float scs[NBOX];
    __shared__ float cl[NBOX];

    const int b = blockIdx.x, t = threadIdx.x;
    const int half = t >> 8, tt = t & 255;          // half-block per slice
    const int slice = 2 * b + half;

    // ---- phase A: load + bitonic sort 512 keys per slice (parallel) ----
    for (int i = tt; i < 512; i += 256)
        skey[half][i] = (i < 3 * TOPK) ? ws[(size_t)slice * 3 * TOPK + i] : 0ull;
    __syncthreads();
    for (int k = 2; k <= 512; k <<= 1) {
        for (int j = k >> 1; j > 0; j >>= 1) {
            for (int i = tt; i < 512; i += 256) {
                int ixj = i ^ j;
                if (ixj > i) {
                    unsigned long long a = skey[half][i], c2 = skey[half][ixj];
                    bool sw = ((i & k) == 0) ? (a < c2) : (a > c2);
                    if (sw) { skey[half][i] = c2; skey[half][ixj] = a; }
                }
            }
            __syncthreads();
        }
    }
    if (tt < TOPK) {
        unsigned long long K = skey[half][tt];
        unsigned vk = (unsigned)(K >> 32);
        unsigned idx = ~((unsigned)K);
        unsigned u = (vk & 0x80000000u) ? (vk & 0x7FFFFFFFu) : ~vk;
        float z = __uint_as_float(u);               // exact original logit
        int c = (int)(idx >> 16);                   // HW == 2^16
        int rem = (int)(idx & 0xFFFFu);
        const float* xb = x + (size_t)slice * SLICE_STRIDE;
        float ysf = (float)(rem >> 8);
        float xsf = (float)(rem & 255);
        float offx = xb[3 * HW + rem];
        float offy = xb[4 * HW + rem];
        float bw = xb[5 * HW + rem] * 4.0f;
        float bh = xb[6 * HW + rem] * 4.0f;
        float cx = (xsf + offx) * 4.0f;
        float cy = (ysf + offy) * 4.0f;
        int slot = half * TOPK + tt;
        bxs4[slot] = make_float4(cx - bw * 0.5f, cy - bh * 0.5f,
                                 cx + bw * 0.5f, cy + bh * 0.5f);
        float sg = 1.0f / (1.0f + expf(-z));
        scs[slot] = (sg > 0.1f) ? sg : 0.0f;
        cl[slot] = (float)c;
    }
    __syncthreads();

    // ---- phase B: wave 0, virtual-position soft-NMS, 1 reduce/round ----
    if (t < 64) {
        float X1[4], Y1[4], X2[4], Y2[4], SC[4], CL4[4], AR[4];
        unsigned CP[4];
        #pragma unroll
        for (int sl = 0; sl < 4; ++sl) {
            int p = sl * 64 + t;
            int q = (p < NBOX) ? p : 0;
            float4 bb = bxs4[q];
            X1[sl] = bb.x; Y1[sl] = bb.y; X2[sl] = bb.z; Y2[sl] = bb.w;
            SC[sl] = (p < NBOX) ? scs[q] : 0.0f;    // phantoms: score 0
            CL4[sl] = cl[q];
            CP[sl] = (unsigned)p;                   // phantoms: cpos 200..255
            // round-invariant (boxes immutable); expression verbatim
            AR[sl] = (X2[sl] - X1[sl] + 1.0f) * (Y2[sl] - Y1[sl] + 1.0f);
        }

        for (int i = 0; i < NBOX; ++i) {
            const unsigned ui = (unsigned)i;
            // single 64-bit key: (score bits, ~((cpos<<8)|orig)).
            // Mask = cpos>=i only: phantoms pass it but have cpos>=200, so
            // any tie (incl. all-zero scores) is won by a real box with
            // smaller cpos; positions i..199 always held by real boxes.
            unsigned long long loc = 0ull;
            #pragma unroll
            for (int sl = 0; sl < 4; ++sl) {
                int p = sl * 64 + t;
                unsigned cd = ~((CP[sl] << 8) | (unsigned)p);
                unsigned long long k =
                    ((unsigned long long)__float_as_uint(SC[sl]) << 32) | cd;
                if (CP[sl] >= ui && k > loc) loc = k;
            }
            unsigned long long kmax = wave_umax64(loc);
            unsigned w32 = ~((unsigned)kmax);       // (m<<8)|worig
            unsigned m = w32 >> 8;                  // current position of max
            unsigned worig = w32 & 0xFFu;           // original slot of max

            float4 pv = bxs4[worig];                // uniform LDS broadcast
            float area_i = (pv.z - pv.x + 1.0f) * (pv.w - pv.y + 1.0f);

            // virtual swap: pos i <-> pos m
            #pragma unroll
            for (int sl = 0; sl < 4; ++sl) {
                unsigned cp = CP[sl];
                unsigned ncp = (cp == ui) ? m : cp;
                ncp = (cp == m) ? ui : ncp;
                CP[sl] = ncp;
            }

            // gaussian decay for current positions > i (formulas verbatim)
            #pragma unroll
            for (int sl = 0; sl < 4; ++sl) {
                int p = sl * 64 + t;
                if ((p < NBOX) && (CP[sl] > ui)) {
                    float x1 = X1[sl], y1 = Y1[sl], x2 = X2[sl], y2 = Y2[sl];
                    float xx1 = fmaxf(pv.x, x1);
                    float yy1 = fmaxf(pv.y, y1);
                    float xx2 = fminf(pv.z, x2);
                    float yy2 = fminf(pv.w, y2);
                    float inter = fmaxf(0.0f, xx2 - xx1 + 1.0f) *
                                  fmaxf(0.0f, yy2 - yy1 + 1.0f);
                    float iou = inter / (area_i + AR[sl] - inter);
                    float w = expf(-(iou * iou) / 0.5f);
                    SC[sl] = w * SC[sl];
                }
            }
        }

        // ---- write outputs: box with final cpos q lands at position q ----
        float* ob  = out + (size_t)b * NBOX * 4;
        float* oc  = out + (size_t)NBATCH * NBOX * 4 + b * NBOX;
        float* os  = out + (size_t)NBATCH * NBOX * 5 + b * NBOX;
        float* okp = out + (size_t)NBATCH * NBOX * 6 + b * NBOX;
        #pragma unroll
        for (int sl = 0; sl < 4; ++sl) {
            int p = sl * 64 + t;
            if (p < NBOX) {
                unsigned q = CP[sl];
                ob[q * 4 + 0] = X1[sl];
                ob[q * 4 + 1] = Y1[sl];
                ob[q * 4 + 2] = X2[sl];
                ob[q * 4 + 3] = Y2[sl];
                oc[q]  = CL4[sl];
                os[q]  = SC[sl];
                okp[q] = (SC[sl] > 0.1f) ? 1.0f : 0.0f;
            }
        }
    }
}

// ===========================================================================
// FALLBACK PATH (round-2 verified kernels, verbatim) — used if ws too small
// ===========================================================================
__global__ __launch_bounds__(1024) void ktopk(const float* __restrict__ x,
                                              float* __restrict__ out) {
    __shared__ unsigned hist[4096];
    __shared__ unsigned long long cand[CAP];
    __shared__ int shB, shB2;
    __shared__ unsigned shAbove, shNcand, shNc;

    const int slice = blockIdx.x;
    const int b = slice >> 1, s = slice & 1;
    const int t = threadIdx.x;
    const float* xb = x + (size_t)slice * SLICE_STRIDE;
    const float4* xb4 = (const float4*)xb;
    const int N4 = HM / 4;

    if (t == 0) { shB = 0; shB2 = 0; shAbove = 0u; shNcand = 0u; shNc = 0u; }
    for (int i = t; i < 4096; i += 1024) hist[i] = 0u;
    __syncthreads();

    for (int i = t; i < N4; i += 1024) {
        float4 v = xb4[i];
        float a[4] = {v.x, v.y, v.z, v.w};
        #pragma unroll
        for (int c_ = 0; c_ < 4; ++c_) {
            unsigned vk = fkey(a[c_]);
            atomicAdd(&hist[vk >> 20], 1u);
        }
    }
    __syncthreads();

    {
        unsigned* tmp = (unsigned*)cand;
        unsigned* src = hist;
        unsigned* dst = tmp;
        for (int d = 1; d < 4096; d <<= 1) {
            for (int i = t; i < 4096; i += 1024) {
                unsigned v = src[i];
                if (i + d < 4096) v += src[i + d];
                dst[i] = v;
            }
            __syncthreads();
            unsigned* sw = src; src = dst; dst = sw;
        }
        for (int i = t; i < 4096; i += 1024) {
            unsigned sb = src[i];
            unsigned sn = (i < 4095) ? src[i + 1] : 0u;
            if (sb >= TOPK && sn < TOPK) { shB = i; shAbove = sn; shNcand = sb; }
        }
        __syncthreads();
    }

    const bool refine = (shNcand > CAP);
    if (refine) {
        for (int i = t; i < 4096; i += 1024) hist[i] = 0u;
        __syncthreads();
        const unsigned Bv = (unsigned)shB;
        for (int i = t; i < N4; i += 1024) {
            float4 v = xb4[i];
            float a[4] = {v.x, v.y, v.z, v.w};
            #pragma unroll
            for (int c_ = 0; c_ < 4; ++c_) {
                unsigned vk = fkey(a[c_]);
                if ((vk >> 20) == Bv) atomicAdd(&hist[(vk >> 8) & 0xFFFu], 1u);
            }
        }
        __syncthreads();
        if (t == 0) {
            unsigned need = TOPK - shAbove, cum = 0u;
            int b2 = 4095;
            for (; b2 >= 0; --b2) { cum += hist[b2]; if (cum >= need) break; }
            shB2 = (b2 < 0) ? 0 : b2;
            shNcand = shAbove + cum;
        }
        __syncthreads();
    }

    {
        const unsigned Bv = (unsigned)shB;
        const unsigned B2v = refine ? (unsigned)shB2 : 0u;
        for (int i = t; i < N4; i += 1024) {
            float4 v = xb4[i];
            float a[4] = {v.x, v.y, v.z, v.w};
            #pragma unroll
            for (int c_ = 0; c_ < 4; ++c_) {
                unsigned vk = fkey(a[c_]);
                unsigned bin = vk >> 20;
                bool q = refine ? (bin > Bv || (bin == Bv && ((vk >> 8) & 0xFFFu) >= B2v))
                                : (bin >= Bv);
                if (q) {
                    unsigned pos = atomicAdd(&shNc, 1u);
                    if (pos < CAP)
                        cand[pos] = ((unsigned long long)vk << 32) |
                                    (unsigned)~(unsigned)(i * 4 + c_);
                }
            }
        }
        __syncthreads();
    }

    unsigned nc = shNc; if (nc > CAP) nc = CAP;
    int P = 128; while (P < (int)nc) P <<= 1;
    for (int i = (int)nc + t; i < P; i += 1024) cand[i] = 0ull;
    __syncthreads();
    for (int k = 2; k <= P; k <<= 1) {
        for (int j = k >> 1; j > 0; j >>= 1) {
            for (int i = t; i < P; i += 1024) {
                int ixj = i ^ j;
                if (ixj > i) {
                    unsigned long long a = cand[i], c2 = cand[ixj];
                    bool sw = ((i & k) == 0) ? (a < c2) : (a > c2);
                    if (sw) { cand[i] = c2; cand[ixj] = a; }
                }
            }
            __syncthreads();
        }
    }

    if (t < TOPK) {
        unsigned long long K = cand[t];
        unsigned vk = (unsigned)(K >> 32);
        unsigned idx = ~((unsigned)K);
        unsigned u = (vk & 0x80000000u) ? (vk & 0x7FFFFFFFu) : ~vk;
        float z = __uint_as_float(u);
        int c = (int)(idx >> 16);
        int rem = (int)(idx & 0xFFFFu);
        float ysf = (float)(rem >> 8);
        float xsf = (float)(rem & 255);
        float offx = xb[3 * HW + rem];
        float offy = xb[4 * HW + rem];
        float bw = xb[5 * HW + rem] * 4.0f;
        float bh = xb[6 * HW + rem] * 4.0f;
        float cx = (xsf + offx) * 4.0f;
        float cy = (ysf + offy) * 4.0f;
        int slot = s * TOPK + t;
        float* ob = out + (size_t)b * NBOX * 4;
        float* oc = out + (size_t)NBATCH * NBOX * 4 + b * NBOX;
        float* os = out + (size_t)NBATCH * NBOX * 5 + b * NBOX;
        ob[slot * 4 + 0] = cx - bw * 0.5f;
        ob[slot * 4 + 1] = cy - bh * 0.5f;
        ob[slot * 4 + 2] = cx + bw * 0.5f;
        ob[slot * 4 + 3] = cy + bh * 0.5f;
        float sg = 1.0f / (1.0f + expf(-z));
        os[slot] = (sg > 0.1f) ? sg : 0.0f;
        oc[slot] = (float)c;
    }
}

__global__ __launch_bounds__(64) void knms(float* __restrict__ out) {
    __shared__ float bxs[NBOX][4];
    __shared__ float scs[NBOX];
    __shared__ float cl[NBOX];

    const int b = blockIdx.x, t = threadIdx.x;
    float* ob  = out + (size_t)b * NBOX * 4;
    float* oc  = out + (size_t)NBATCH * NBOX * 4 + b * NBOX;
    float* os  = out + (size_t)NBATCH * NBOX * 5 + b * NBOX;
    float* okp = out + (size_t)NBATCH * NBOX * 6 + b * NBOX;

    for (int p = t; p < NBOX; p += 64) {
        bxs[p][0] = ob[p * 4 + 0];
        bxs[p][1] = ob[p * 4 + 1];
        bxs[p][2] = ob[p * 4 + 2];
        bxs[p][3] = ob[p * 4 + 3];
        scs[p] = os[p];
        cl[p]  = oc[p];
    }
    __syncthreads();

    unsigned long long local = 0ull;
    for (int p = t; p < NBOX; p += 64) {
        unsigned long long k =
            ((unsigned long long)__float_as_uint(scs[p]) << 32) | (unsigned)~(unsigned)p;
        if (k > local) local = k;
    }
    #pragma unroll
    for (int off = 32; off > 0; off >>= 1) {
        unsigned long long o = __shfl_xor(local, off);
        if (o > local) local = o;
    }
    unsigned long long kmax = local;

    for (int i = 0; i < NBOX; ++i) {
        int m = (int)(~((unsigned)kmax));
        if (t == 0 && m != i) {
            #pragma unroll
            for (int k = 0; k < 4; ++k) {
                float tmp = bxs[i][k]; bxs[i][k] = bxs[m][k]; bxs[m][k] = tmp;
            }
            float ts = scs[i]; scs[i] = scs[m]; scs[m] = ts;
            float tc = cl[i];  cl[i]  = cl[m];  cl[m]  = tc;
        }
        __syncthreads();

        float b0 = bxs[i][0], b1 = bxs[i][1], b2 = bxs[i][2], b3 = bxs[i][3];
        float area_i = (b2 - b0 + 1.0f) * (b3 - b1 + 1.0f);

        local = 0ull;
        for (int p = i + 1 + t; p < NBOX; p += 64) {
            float x1 = bxs[p][0], y1 = bxs[p][1], x2 = bxs[p][2], y2 = bxs[p][3];
            float areas = (x2 - x1 + 1.0f) * (y2 - y1 + 1.0f);
            float xx1 = fmaxf(b0, x1);
            float yy1 = fmaxf(b1, y1);
            float xx2 = fminf(b2, x2);
            float yy2 = fminf(b3, y2);
            float inter = fmaxf(0.0f, xx2 - xx1 + 1.0f) * fmaxf(0.0f, yy2 - yy1 + 1.0f);
            float iou = inter / (area_i + areas - inter);
            float w = expf(-(iou * iou) / 0.5f);
            float ns = w * scs[p];
            scs[p] = ns;
            unsigned long long k =
                ((unsigned long long)__float_as_uint(ns) << 32) | (unsigned)~(unsigned)p;
            if (k > local) local = k;
        }
        __syncthreads();
        #pragma unroll
        for (int off = 32; off > 0; off >>= 1) {
            unsigned long long o = __shfl_xor(local, off);
            if (o > local) local = o;
        }
        kmax = local;
    }
    __syncthreads();

    for (int p = t; p < NBOX; p += 64) {
        ob[p * 4 + 0] = bxs[p][0];
        ob[p * 4 + 1] = bxs[p][1];
        ob[p * 4 + 2] = bxs[p][2];
        ob[p * 4 + 3] = bxs[p][3];
        oc[p]  = cl[p];
        os[p]  = scs[p];
        okp[p] = (scs[p] > 0.1f) ? 1.0f : 0.0f;
    }
}

extern "C" void kernel_launch(void* const* d_in, const int* in_sizes, int n_in,
                              void* d_out, int out_size, void* d_ws, size_t ws_size,
                              hipStream_t stream) {
    const float* x = (const float*)d_in[0];
    float* out = (float*)d_out;
    if (d_ws != nullptr && ws_size >= WS_NEED) {
        kcol<<<192, 1024, 0, stream>>>(x, (unsigned long long*)d_ws);
        knms4<<<NBATCH, 512, 0, stream>>>(x, (const unsigned long long*)d_ws, out);
    } else {
        ktopk<<<2 * NBATCH, 1024, 0, stream>>>(x, out);
        knms<<<NBATCH, 64, 0, stream>>>(out);
    }
}